// Round 13
// baseline (431.786 us; speedup 1.0000x reference)
//
#include <hip/hip_runtime.h>

#define NN 50000
#define EE 400000
#define CC 128
#define TT 2
#define NT16R 3128  // padded 16-node tiles per type (ceil(50048/16))
#define KPB 8      // edges per thread in scatter batching
#define KPC 16     // edges per thread per pass in partitioned count
#define BINS 2048  // dest bins per count block (LDS histogram)
#define CNTB ((NN + BINS - 1) / BINS)        // 25 count blocks per type
#define SCB ((NN + 1023) / 1024)
#define EB ((EE + 256 * KPB - 1) / (256 * KPB))  // 196 edge blocks per type
#define CVTB (NT16R / 4)                     // 782 cvt blocks per type
#define PREPN (2 * 384 * 128 + 2 * 128 * 128 + 2 * 384)
#define PREPB ((PREPN + 255) / 256)          // 515 prep blocks per layer
#define GB ((NN + 31) / 32)                  // 1563 gemm blocks per type

typedef float floatx4 __attribute__((ext_vector_type(4)));
typedef float floatx2 __attribute__((ext_vector_type(2)));
typedef _Float16 half8 __attribute__((ext_vector_type(8)));
typedef _Float16 half2t __attribute__((ext_vector_type(2)));

__device__ __forceinline__ unsigned pk2h(float a, float b) {
    return __builtin_bit_cast(unsigned, __builtin_amdgcn_cvt_pkrtz(a, b));
}
// tanh-approx gelu (jax.nn.gelu default approximate=True), NaN-free form
__device__ __forceinline__ float gelu_f(float x) {
    float u = 0.7978845608028654f * (x + 0.044715f * x * x * x);
    float t = __expf(2.f * u);
    return x * (1.f - 1.f / (t + 1.f));
}

// packed f32 fma: lowers to v_pk_fma_f32 on gfx90a+
__device__ __forceinline__ floatx2 pkfma(floatx2 a, floatx2 b, floatx2 c) {
#if __has_builtin(__builtin_elementwise_fma)
    return __builtin_elementwise_fma(a, b, c);
#else
    floatx2 r;
    r.x = fmaf(a.x, b.x, c.x);
    r.y = fmaf(a.y, b.y, c.y);
    return r;
#endif
}

// ---- OCP e4m3 pack/unpack (HW cvt on gfx950; SW fallback) ----
__device__ __forceinline__ unsigned pk_fp8x4(float a, float b, float c, float d) {
#if __has_builtin(__builtin_amdgcn_cvt_pk_fp8_f32)
    int v = 0;
    v = __builtin_amdgcn_cvt_pk_fp8_f32(a, b, v, false);
    v = __builtin_amdgcn_cvt_pk_fp8_f32(c, d, v, true);
    return (unsigned)v;
#else
    auto enc = [](float x) -> unsigned {
        unsigned u = __float_as_uint(x);
        unsigned s = (u >> 24) & 0x80;
        int e = (int)((u >> 23) & 0xff);
        unsigned m = u & 0x7fffff;
        if (e == 0) return s;
        int ne = e - 127 + 7;
        if (ne <= 0) {
            unsigned full = (1u << 23) | m;
            int sh = 21 - ne;
            if (sh > 24) return s;
            unsigned r = full >> sh;
            unsigned rem = full & ((1u << sh) - 1);
            unsigned half = 1u << (sh - 1);
            if (rem > half || (rem == half && (r & 1))) r++;
            return s | (r & 0x7f);
        }
        unsigned r = m >> 20;
        unsigned rem = m & 0xfffff;
        if (rem > 0x80000 || (rem == 0x80000 && (r & 1))) {
            r++;
            if (r == 8) { r = 0; ne++; }
        }
        if (ne > 15) return s | 0x7e;
        return s | ((unsigned)ne << 3) | r;
    };
    return enc(a) | (enc(b) << 8) | (enc(c) << 16) | (enc(d) << 24);
#endif
}

template <bool HI>
__device__ __forceinline__ floatx2 upk_fp8(unsigned v) {
#if __has_builtin(__builtin_amdgcn_cvt_pk_f32_fp8)
    return __builtin_amdgcn_cvt_pk_f32_fp8((int)v, HI);
#else
    auto dec = [](unsigned b) -> float {
        unsigned s = b & 0x80;
        unsigned e = (b >> 3) & 0xf;
        unsigned m = b & 7;
        float val;
        if (e == 0) val = (float)m * (1.f / 512.f);
        else val = (1.f + (float)m * 0.125f) * exp2f((float)e - 7.f);
        return s ? -val : val;
    };
    unsigned base = HI ? (v >> 16) : v;
    floatx2 r;
    r.x = dec(base & 0xff);
    r.y = dec((base >> 8) & 0xff);
    return r;
#endif
}

// block-local int64 probe: int64 node arrays have zero high words
__device__ __forceinline__ int detect_is64(const int* __restrict__ ei, int* sflag) {
    if (threadIdx.x == 0) {
        int orv = 0;
#pragma unroll
        for (int i = 1; i < 64; i += 2) orv |= ei[i];
        *sflag = (orv == 0) ? 1 : 0;
    }
    __syncthreads();
    return *sflag;
}

// Partitioned count: block owns dest range [bx*BINS, bx*BINS+BINS).
// Scans the WHOLE dest column (L2-resident re-reads) and counts owned dests
// with LDS atomics -> ZERO device-scope atomics.  Rank = LDS-atomic return
// (neighbor order within a dest is irrelevant: attention aggregates by sum).
// Bins written out as counts directly (no memset pass needed).
__device__ __forceinline__ void count_body(const int* __restrict__ ei,
                                           int* __restrict__ counts,
                                           unsigned short* __restrict__ rank,
                                           int e, int bx, int* bins, int* sflag) {
    int tid = threadIdx.x;
    for (int i = tid; i < BINS; i += 256) bins[i] = 0;
    int is64 = detect_is64(ei, sflag);  // its barrier also publishes zeroed bins
    int base = bx * BINS;
    const size_t db = (size_t)(e * 2 + 1) * EE;
    for (int it = 0; it < EE; it += 256 * KPC) {
        int d[KPC];
        bool ok[KPC];
#pragma unroll
        for (int k = 0; k < KPC; k++) {
            int j = it + k * 256 + tid;
            ok[k] = j < EE;
            int jc = ok[k] ? j : 0;
            int dd = is64 ? ei[(db + jc) * 2] : ei[db + jc];
            d[k] = min(max(dd, 0), NN - 1);
        }
#pragma unroll
        for (int k = 0; k < KPC; k++) {
            int j = it + k * 256 + tid;
            int local = d[k] - base;
            if (ok[k] && local >= 0 && local < BINS) {
                int r = atomicAdd(&bins[local], 1);  // LDS atomic
                rank[(size_t)e * EE + j] = (unsigned short)r;
            }
        }
    }
    __syncthreads();
    for (int i = tid; i < BINS; i += 256) {
        int g = base + i;
        if (g < NN) counts[e * NN + g] = bins[i];
    }
}

// Atomic-free scatter: pos = rowptr[di] + rank[j]; 8 edges/thread for ILP.
__device__ __forceinline__ void scatter_body(const int* __restrict__ ei,
                                             const int* __restrict__ rowptr,
                                             const unsigned short* __restrict__ rank,
                                             int* __restrict__ csr,
                                             int e, int bx, int* sflag) {
    int is64 = detect_is64(ei, sflag);
    int tid = threadIdx.x;
    int base = bx * (256 * KPB);
    const size_t sb = (size_t)(e * 2 + 0) * EE;
    const size_t db = (size_t)(e * 2 + 1) * EE;
    int si[KPB], di[KPB], rk[KPB];
#pragma unroll
    for (int k = 0; k < KPB; k++) {
        int j = base + k * 256 + tid;
        int jc = (j < EE) ? j : 0;
        si[k] = is64 ? ei[(sb + jc) * 2] : ei[sb + jc];
        di[k] = is64 ? ei[(db + jc) * 2] : ei[db + jc];
        rk[k] = rank[(size_t)e * EE + jc];
    }
    int pos[KPB];
#pragma unroll
    for (int k = 0; k < KPB; k++) {
        di[k] = min(max(di[k], 0), NN - 1);
        si[k] = min(max(si[k], 0), NN - 1);
    }
#pragma unroll
    for (int k = 0; k < KPB; k++) pos[k] = rowptr[e * (NN + 1) + di[k]] + rk[k];
#pragma unroll
    for (int k = 0; k < KPB; k++) {
        int j = base + k * 256 + tid;
        if (j < EE) csr[(size_t)e * EE + pos[k]] = si[k];
    }
}

// cvt: x f32 row-major -> xs f16 swizzled [t][tile][kt][quad][ln][8] via LDS
// transpose.  Pad tiles filled with clamped rows.  Both global sides coalesced.
__device__ __forceinline__ void cvt_body(const float* __restrict__ x,
                                         _Float16* __restrict__ xs,
                                         int t, int bx, _Float16* sm) {
    int tid = threadIdx.x;
    int node0 = bx * 64;
#pragma unroll
    for (int p = 0; p < 8; p++) {
        int c = p * 256 + tid;
        int row = c >> 5, ch = c & 31;
        int node = min(node0 + row, NN - 1);
        float4 v = *(const float4*)(x + ((size_t)t * NN + node) * CC + ch * 4);
        uint2 o;
        o.x = pk2h(v.x, v.y);
        o.y = pk2h(v.z, v.w);
        *(uint2*)(sm + row * 132 + ch * 4) = o;
    }
    __syncthreads();
    _Float16* xt = xs + (size_t)t * NT16R * 2048;
#pragma unroll
    for (int p = 0; p < 4; p++) {
        int c = p * 256 + tid;
        int tl = c >> 8, kt = (c >> 6) & 3, l = c & 63;
        int q = l >> 4, ln = l & 15;
        *(uint4*)(xt + ((size_t)(bx * 4 + tl) * 4 + kt) * 512 + l * 8) =
            *(const uint4*)(sm + (tl * 16 + ln) * 132 + kt * 32 + q * 8);
    }
}

// prep: composed weights (idx-based mapping, round-11 proven), swizzled A-frag:
//   W2[lt][mt(24)][kt(4)][lane(64)][8]; n in [0,384):
//   q*p_rel*scale*log2e | Wk a_rel | Wv m_rel  (log2e folded -> attn uses exp2)
__device__ __forceinline__ void prep_body(
    const float* __restrict__ Wk, const float* __restrict__ Wq,
    const float* __restrict__ Wv, const float* __restrict__ Wa,
    const float* __restrict__ bk, const float* __restrict__ bq,
    const float* __restrict__ bv,
    const float* __restrict__ a_rel, const float* __restrict__ m_rel,
    const float* __restrict__ p_rel,
    _Float16* __restrict__ W2, _Float16* __restrict__ Wa2,
    float* __restrict__ beff, int l, int idx) {
    // 1/sqrt(32) * log2(e): softmax(exp2(x*log2e)) == softmax(exp(x))
    const float SCALE = 0.17677669529663687f * 1.4426950408889634f;
    if (idx < 2 * 384 * 128) {
        int t = idx / (384 * 128);
        int r = idx - t * 384 * 128;
        int n = r >> 7, k = r & 127;
        float val;
        if (n < 128) {
            val = Wq[((l * 2 + t) * 128 + k) * 128 + n] *
                  p_rel[(l * 2 + (1 - t)) * 4 + (n >> 5)] * SCALE;
        } else if (n < 256) {
            int nn = n - 128, h = nn >> 5, f = nn & 31;
            const float* wr = Wk + ((l * 2 + t) * 128 + k) * 128 + h * 32;
            const float* ar = a_rel + (((l * 2 + t) * 4 + h) * 32) * 32 + f;
            float s = 0.f;
            for (int d = 0; d < 32; d++) s += wr[d] * ar[d * 32];
            val = s;
        } else {
            int nn = n - 256, h = nn >> 5, f = nn & 31;
            const float* wr = Wv + ((l * 2 + t) * 128 + k) * 128 + h * 32;
            const float* mr = m_rel + (((l * 2 + t) * 4 + h) * 32) * 32 + f;
            float s = 0.f;
            for (int d = 0; d < 32; d++) s += wr[d] * mr[d * 32];
            val = s;
        }
        W2[(((size_t)(l * 2 + t) * 24 + (n >> 4)) * 4 + (k >> 5)) * 512 +
           (((k & 31) >> 3) * 16 + (n & 15)) * 8 + (k & 7)] = (_Float16)val;
    } else if (idx < 2 * 384 * 128 + 2 * 128 * 128) {
        int r = idx - 2 * 384 * 128;
        int t = r / (128 * 128);
        r -= t * 128 * 128;
        int n = r >> 7, k = r & 127;
        float val = Wa[((l * 2 + t) * 128 + k) * 128 + n];
        Wa2[(((size_t)(l * 2 + t) * 8 + (n >> 4)) * 4 + (k >> 5)) * 512 +
            (((k & 31) >> 3) * 16 + (n & 15)) * 8 + (k & 7)] = (_Float16)val;
    } else if (idx < PREPN) {
        int r = idx - (2 * 384 * 128 + 2 * 128 * 128);
        int t = r / 384, n = r - t * 384;
        float val;
        if (n < 128) {
            val = bq[(l * 2 + t) * 128 + n] * p_rel[(l * 2 + (1 - t)) * 4 + (n >> 5)] * SCALE;
        } else if (n < 256) {
            int nn = n - 128, h = nn >> 5, f = nn & 31;
            float s = 0.f;
            for (int d = 0; d < 32; d++)
                s += bk[(l * 2 + t) * 128 + h * 32 + d] *
                     a_rel[(((l * 2 + t) * 4 + h) * 32 + d) * 32 + f];
            val = s;
        } else {
            int nn = n - 256, h = nn >> 5, f = nn & 31;
            float s = 0.f;
            for (int d = 0; d < 32; d++)
                s += bv[(l * 2 + t) * 128 + h * 32 + d] *
                     m_rel[(((l * 2 + t) * 4 + h) * 32 + d) * 32 + f];
            val = s;
        }
        beff[(l * 2 + t) * 384 + n] = val;
    }
}

// FUSED independent pre-work: count (x<CNTB) | cvt (x<CNTB+CVTB) | prep (rest).
// All three depend only on kernel inputs; co-scheduling hides the count
// blocks' L2-scan latency under cvt/prep memory work.
__global__ __launch_bounds__(256) void k_fuse_pre(
    const int* __restrict__ ei, int* __restrict__ counts,
    unsigned short* __restrict__ rank,
    const float* __restrict__ x, _Float16* __restrict__ xs,
    const float* __restrict__ Wk, const float* __restrict__ Wq,
    const float* __restrict__ Wv, const float* __restrict__ Wa,
    const float* __restrict__ bk, const float* __restrict__ bq,
    const float* __restrict__ bv,
    const float* __restrict__ a_rel, const float* __restrict__ m_rel,
    const float* __restrict__ p_rel,
    _Float16* __restrict__ W2, _Float16* __restrict__ Wa2,
    float* __restrict__ beff) {
    __shared__ int sbuf[4224];  // 16.9 KB: cvt f16 view / count bins (8 KB)
    __shared__ int sflag;
    if (blockIdx.x < CNTB) {
        count_body(ei, counts, rank, blockIdx.y, blockIdx.x, sbuf, &sflag);
    } else if (blockIdx.x < CNTB + CVTB) {
        cvt_body(x, xs, blockIdx.y, blockIdx.x - CNTB, (_Float16*)sbuf);
    } else {
        prep_body(Wk, Wq, Wv, Wa, bk, bq, bv, a_rel, m_rel, p_rel, W2, Wa2, beff,
                  blockIdx.y, (blockIdx.x - CNTB - CVTB) * 256 + (int)threadIdx.x);
    }
}

// ---- scan phase 1: per-block local prefixes + raw block sums ----
__global__ __launch_bounds__(256) void k_scan1(const int* __restrict__ counts,
                                               int* __restrict__ rowptr,
                                               int* __restrict__ bsum) {
    int e = blockIdx.y, b = blockIdx.x;
    int tid = threadIdx.x, lane = tid & 63, wid = tid >> 6;
    __shared__ int wsum[4];
    int base = b * 1024 + tid * 4;
    int v[4], s = 0;
#pragma unroll
    for (int k2 = 0; k2 < 4; k2++) {
        int i = base + k2;
        v[k2] = (i < NN) ? counts[e * NN + i] : 0;
        s += v[k2];
    }
    int incl = s;
#pragma unroll
    for (int off = 1; off < 64; off <<= 1) {
        int t2 = __shfl_up(incl, off);
        if (lane >= off) incl += t2;
    }
    if (lane == 63) wsum[wid] = incl;
    __syncthreads();
    int woff = 0;
    for (int w2 = 0; w2 < wid; w2++) woff += wsum[w2];
    int excl = woff + incl - s;
#pragma unroll
    for (int k2 = 0; k2 < 4; k2++) {
        int i = base + k2;
        if (i < NN) rowptr[e * (NN + 1) + i] = excl;
        excl += v[k2];
    }
    if (tid == 255) bsum[e * SCB + b] = woff + incl;
}

// ---- scan phase 2+3 merged: each block re-scans the 49 raw block sums
// itself (one wave), derives its own offset + grand total, applies. ----
__global__ __launch_bounds__(256) void k_scan23(int* __restrict__ rowptr,
                                                const int* __restrict__ bsum) {
    __shared__ int soff2[2];  // {block offset, grand total}
    int e = blockIdx.y, b = blockIdx.x;
    int tid = threadIdx.x, lane = tid & 63, wv = tid >> 6;
    if (wv == 0) {
        int v = (lane < SCB) ? bsum[e * SCB + lane] : 0;
        int incl = v;
#pragma unroll
        for (int off = 1; off < 64; off <<= 1) {
            int t2 = __shfl_up(incl, off);
            if (lane >= off) incl += t2;
        }
        if (lane == b) soff2[0] = incl - v;         // exclusive prefix at b
        if (lane == SCB - 1) soff2[1] = incl;       // total
    }
    __syncthreads();
    int off = soff2[0];
    int base = b * 1024 + tid * 4;
#pragma unroll
    for (int k2 = 0; k2 < 4; k2++) {
        int i = base + k2;
        if (i < NN) rowptr[e * (NN + 1) + i] += off;
    }
    if (b == 0 && tid == 0) rowptr[e * (NN + 1) + NN] = soff2[1];
}

// Transposed GEMM body, swizzled operands (every frag load = base + lane*16,
// coalesced), LDS-staged coalesced stores into mixed-precision qkv rows:
// node row = 512 B: [0,256) q f16 | [256,512) k/v fp8 INTERLEAVED in 16B granules:
//   granule g (byte 256+g*16): k feats [g*8,g*8+8) | v feats [g*8,g*8+8).
template <int NT, int COL0>
__device__ __forceinline__ void gemm_body(const _Float16* __restrict__ xs,
                                          const _Float16* __restrict__ W2,
                                          const float* __restrict__ beff,
                                          unsigned char* __restrict__ qkv8,
                                          int l, int t, int bx,
                                          unsigned char* tile) {
    constexpr int RB = (NT == 6) ? 512 : 256;  // tile row bytes
    constexpr int RS = RB + 16;                // LDS row stride
    int tid = threadIdx.x;
    int wid = tid >> 6, lane = tid & 63;
    int quad = lane >> 4, ln = lane & 15;
    int node0 = bx * 32;
    int tile0 = bx * 2;
    int lt = l * 2 + t;
    const _Float16* Wt = W2 + (size_t)lt * 24 * 2048;
    const _Float16* xt = xs + (size_t)t * NT16R * 2048;
    half8 bf[2][4];
#pragma unroll
    for (int ns = 0; ns < 2; ns++)
#pragma unroll
        for (int kt = 0; kt < 4; kt++)
            bf[ns][kt] = *(const half8*)(xt + ((size_t)(tile0 + ns) * 4 + kt) * 512 + lane * 8);
    floatx4 acc[NT][2];
#pragma unroll
    for (int nt = 0; nt < NT; nt++)
#pragma unroll
        for (int ns = 0; ns < 2; ns++) acc[nt][ns] = (floatx4){0.f, 0.f, 0.f, 0.f};
#pragma unroll
    for (int nt = 0; nt < NT; nt++) {
        int mt = COL0 / 16 + wid * NT + nt;
#pragma unroll
        for (int kt = 0; kt < 4; kt++) {
            half8 af = *(const half8*)(Wt + ((size_t)mt * 4 + kt) * 512 + lane * 8);
            acc[nt][0] = __builtin_amdgcn_mfma_f32_16x16x32_f16(af, bf[0][kt], acc[nt][0], 0, 0, 0);
            acc[nt][1] = __builtin_amdgcn_mfma_f32_16x16x32_f16(af, bf[1][kt], acc[nt][1], 0, 0, 0);
        }
    }
    // stage to LDS (+bias): q comps -> f16 pairs, k/v comps -> fp8x4 interleaved granules
#pragma unroll
    for (int nt = 0; nt < NT; nt++) {
        int c0 = COL0 + wid * NT * 16 + nt * 16 + quad * 4;
        float4 b4 = *(const float4*)(beff + (l * 2 + t) * 384 + c0);
#pragma unroll
        for (int ns = 0; ns < 2; ns++) {
            int nl = ns * 16 + ln;
            float v0 = acc[nt][ns][0] + b4.x, v1 = acc[nt][ns][1] + b4.y;
            float v2 = acc[nt][ns][2] + b4.z, v3 = acc[nt][ns][3] + b4.w;
            unsigned char* rowp = tile + nl * RS;
            if (c0 < 128) {
                uint2 o;
                o.x = pk2h(v0, v1);
                o.y = pk2h(v2, v3);
                *(uint2*)(rowp + 2 * c0) = o;
            } else {
                int f0 = c0 & 127;            // feature index within k (or v)
                int isV = (c0 >= 256);
                int loff = (f0 >> 3) * 16 + (f0 & 7) + isV * 8 +
                           ((COL0 == 128) ? 0 : 256);
                *(unsigned*)(rowp + loff) = pk_fp8x4(v0, v1, v2, v3);
            }
        }
    }
    __syncthreads();
    // coalesced copy-out: 16B chunks, contiguous RB bytes per node row
    constexpr int CPR = RB / 16;
    constexpr int PASSES = (32 * CPR) / 256;
#pragma unroll
    for (int p = 0; p < PASSES; p++) {
        int c = p * 256 + tid;
        int row = c / CPR, ch = c - row * CPR;
        int node = node0 + row;
        if (node < NN)
            *(uint4*)(qkv8 + ((size_t)t * NN + node) * 512 + (COL0 ? 256 : 0) + ch * 16) =
                *(const uint4*)(tile + row * RS + ch * 16);
    }
}

// FUSED mid stage: scatter (x<EB) | layer-0 full-qkv GEMM (rest).
// scatter needs {rowptr, rank} (ready after scan23); gemm needs {xs, W2, beff}
// (ready after fuse_pre) -> independent, co-scheduled.  Scatter's scattered
// stores hide under the GEMM's MFMA work.
__global__ __launch_bounds__(256) void k_fuse_mid(
    const int* __restrict__ ei, const int* __restrict__ rowptr,
    const unsigned short* __restrict__ rank, int* __restrict__ csr,
    const _Float16* __restrict__ xs, const _Float16* __restrict__ W2,
    const float* __restrict__ beff, unsigned char* __restrict__ qkv8) {
    __shared__ unsigned char tile[32 * 528];  // gemm<6,0>: RS=528
    if (blockIdx.x < EB) {
        scatter_body(ei, rowptr, rank, csr, blockIdx.y, blockIdx.x, (int*)tile);
    } else {
        gemm_body<6, 0>(xs, W2, beff, qkv8, 0, blockIdx.y, blockIdx.x - EB, tile);
    }
}

// Layer-1 merged pair: y=0 -> t0 q cols [0,128); y=1 -> t1 k/v cols [128,384).
__global__ __launch_bounds__(256) void k_gemm_l1(const _Float16* __restrict__ xs,
                                                 const _Float16* __restrict__ W2,
                                                 const float* __restrict__ beff,
                                                 unsigned char* __restrict__ qkv8) {
    __shared__ unsigned char tile[32 * 272];  // RB=256 for both branches
    if (blockIdx.y == 0)
        gemm_body<2, 0>(xs, W2, beff, qkv8, 1, 0, blockIdx.x, tile);
    else
        gemm_body<4, 128>(xs, W2, beff, qkv8, 1, 1, blockIdx.x, tile);
}

// Dest-centric attention.  Wave = 1 dest node; 64 lanes = 4 edge slots x 16 segs.
// q f16; k/v fp8 interleaved 16B granules -> ONE uint4 gather per lane per edge.
// csr indices prefetched one chunk ahead of gathers (breaks the csr->gather
// serial latency chain); rowptr via scalar loads; tail slots exec-masked.
// Logits arrive pre-scaled by log2e (prep) -> exp2 for softmax.
__global__ __launch_bounds__(256) void k_attn(const unsigned char* __restrict__ qkv8,
                                              const int* __restrict__ rowptr,
                                              const int* __restrict__ csr,
                                              _Float16* __restrict__ outg) {
    int t = blockIdx.y;
    int e = 1 - t;
    int st = 1 - t;
    int wid = threadIdx.x >> 6, lane = threadIdx.x & 63;
    int n = __builtin_amdgcn_readfirstlane(blockIdx.x * 4 + wid);
    int e4 = lane >> 4, s = lane & 15;
    // n is SGPR -> these become scalar loads issued on the scalar pipe
    int r0 = rowptr[e * (NN + 1) + n];
    int r1 = rowptr[e * (NN + 1) + n + 1];
    const int* csrp = csr + (size_t)e * EE;
    const unsigned char* sbase = qkv8 + (size_t)st * NN * 512;
    uint4 qd = *(const uint4*)(qkv8 + ((size_t)t * NN + n) * 512 + s * 16);

    floatx2 acc2[4];
#pragma unroll
    for (int i = 0; i < 4; i++) acc2[i] = (floatx2){0.f, 0.f};
    float lsum = 0.f;
    floatx2 q2[4];

    auto process = [&](const uint4& u, float msk) {
        // u.x|u.y = k feats [s*8, s*8+8); u.z|u.w = v feats [s*8, s*8+8)
        floatx2 p2 = q2[0] * upk_fp8<false>(u.x);
        p2 = pkfma(q2[1], upk_fp8<true>(u.x), p2);
        p2 = pkfma(q2[2], upk_fp8<false>(u.y), p2);
        p2 = pkfma(q2[3], upk_fp8<true>(u.y), p2);
        float p = p2.x + p2.y;
        p += __shfl_xor(p, 1);
        p += __shfl_xor(p, 2);  // 4 segs of one head now hold the full head dot
        float w = exp2f(p) * msk;  // q pre-scaled by log2e
        lsum += w;
        floatx2 w2 = (floatx2){w, w};
        acc2[0] = pkfma(w2, upk_fp8<false>(u.z), acc2[0]);
        acc2[1] = pkfma(w2, upk_fp8<true>(u.z), acc2[1]);
        acc2[2] = pkfma(w2, upk_fp8<false>(u.w), acc2[2]);
        acc2[3] = pkfma(w2, upk_fp8<true>(u.w), acc2[3]);
    };

    if (r0 < r1) {
        int j = r0;
        // prologue: csr indices for chunks j and j+4 both in flight, then gather j
        int iA = csrp[min(j + e4, r1 - 1)];
        int iB = csrp[min(j + 4 + e4, r1 - 1)];
        uint4 uA = (uint4){0u, 0u, 0u, 0u};
        if (j + e4 < r1) uA = *(const uint4*)(sbase + (size_t)iA * 512 + 256 + s * 16);
        // convert q while the loads fly
        {
            half2t h0 = __builtin_bit_cast(half2t, qd.x), h1 = __builtin_bit_cast(half2t, qd.y);
            half2t h2 = __builtin_bit_cast(half2t, qd.z), h3 = __builtin_bit_cast(half2t, qd.w);
            q2[0] = (floatx2){(float)h0.x, (float)h0.y};
            q2[1] = (floatx2){(float)h1.x, (float)h1.y};
            q2[2] = (floatx2){(float)h2.x, (float)h2.y};
            q2[3] = (floatx2){(float)h3.x, (float)h3.y};
        }
        for (; j + 8 < r1; j += 4) {
            // chunk j+4 is fully valid here (j+4+e4 <= j+7 < r1)
            uint4 uB = *(const uint4*)(sbase + (size_t)iB * 512 + 256 + s * 16);
            iB = csrp[min(j + 8 + e4, r1 - 1)];  // prefetch indices one chunk ahead
            process(uA, 1.f);
            uA = uB;
        }
        if (j + 4 < r1) {
            // chunk j full, chunk j+4 partial
            uint4 uB = (uint4){0u, 0u, 0u, 0u};
            float mB = (j + 4 + e4 < r1) ? 1.f : 0.f;
            if (j + 4 + e4 < r1)
                uB = *(const uint4*)(sbase + (size_t)iB * 512 + 256 + s * 16);
            process(uA, 1.f);
            process(uB, mB);
        } else {
            process(uA, (j + e4 < r1) ? 1.f : 0.f);
        }
    }
    float accf[8] = {acc2[0].x, acc2[0].y, acc2[1].x, acc2[1].y,
                     acc2[2].x, acc2[2].y, acc2[3].x, acc2[3].y};
#pragma unroll
    for (int i = 0; i < 8; i++) {
        accf[i] += __shfl_xor(accf[i], 16);
        accf[i] += __shfl_xor(accf[i], 32);
    }
    lsum += __shfl_xor(lsum, 16);
    lsum += __shfl_xor(lsum, 32);
    float inv = 1.f / (lsum + 1e-16f);
    if (e4 == 0) {
        uint4 o;
        o.x = pk2h(accf[0] * inv, accf[1] * inv);
        o.y = pk2h(accf[2] * inv, accf[3] * inv);
        o.z = pk2h(accf[4] * inv, accf[5] * inv);
        o.w = pk2h(accf[6] * inv, accf[7] * inv);
        *(uint4*)(outg + ((size_t)t * NN + n) * CC + s * 8) = o;
    }
}

// Transposed epilogue, swizzled Wa/x operands.
// o = gelu(outg) @ Wa + ba ; skip-blend ; LayerNorm ; ReLU.
// f16 path: LDS-staged swizzled xb_next writes (16.9 KB LDS -> 8 blocks/CU).
// f32 path (l=1): DIRECT float4 stores (no LDS, no barriers).
// Residual xs loads issued before the MFMA loop to hide their latency.
__global__ __launch_bounds__(256) void k_epilogue(
    const _Float16* __restrict__ outg, const _Float16* __restrict__ Wa2,
    const float* __restrict__ ba, const float* __restrict__ skipv,
    const float* __restrict__ ln_g, const float* __restrict__ ln_b,
    const _Float16* __restrict__ xs_cur, _Float16* __restrict__ xs_next,
    float* __restrict__ xout, int l) {
    __shared__ _Float16 smem_h[64 * 132];  // f16-only staging (f32 path bypasses LDS)
    int t = blockIdx.y;
    int tid = threadIdx.x;
    int wid = tid >> 6, lane = tid & 63;
    int quad = lane >> 4, ln = lane & 15;
    int node0 = blockIdx.x * 64;
    int nloc = wid * 16 + ln;
    int node = node0 + nloc;
    int arow = min(node, NN - 1);
    const _Float16* grow = outg + ((size_t)t * NN + arow) * CC;
    // issue all gelu-input loads first
    uint4 gd4[4];
#pragma unroll
    for (int kt = 0; kt < 4; kt++) gd4[kt] = *(const uint4*)(grow + kt * 32 + quad * 8);
    // issue residual loads early: their latency hides under gelu + MFMA
    const _Float16* xt = xs_cur + (size_t)t * NT16R * 2048;
    int tileR = arow >> 4, lnR = arow & 15;
    uint2 xw8[8];
#pragma unroll
    for (int nt = 0; nt < 8; nt++) {
        int c0 = nt * 16 + quad * 4;
        xw8[nt] = *(const uint2*)(xt + ((size_t)tileR * 4 + (c0 >> 5)) * 512 +
                                  (((c0 >> 3) & 3) * 16 + lnR) * 8 + (c0 & 7));
    }
    half8 bf[4];
#pragma unroll
    for (int kt = 0; kt < 4; kt++) {
        uint4 gd = gd4[kt];
        half2t h0 = __builtin_bit_cast(half2t, gd.x), h1 = __builtin_bit_cast(half2t, gd.y);
        half2t h2 = __builtin_bit_cast(half2t, gd.z), h3 = __builtin_bit_cast(half2t, gd.w);
        uint4 pk;
        pk.x = pk2h(gelu_f((float)h0.x), gelu_f((float)h0.y));
        pk.y = pk2h(gelu_f((float)h1.x), gelu_f((float)h1.y));
        pk.z = pk2h(gelu_f((float)h2.x), gelu_f((float)h2.y));
        pk.w = pk2h(gelu_f((float)h3.x), gelu_f((float)h3.y));
        bf[kt] = __builtin_bit_cast(half8, pk);
    }
    const _Float16* Wt = Wa2 + (size_t)(l * 2 + t) * 8 * 2048;
    floatx4 acc[8];
#pragma unroll
    for (int nt = 0; nt < 8; nt++) acc[nt] = (floatx4){0.f, 0.f, 0.f, 0.f};
#pragma unroll
    for (int nt = 0; nt < 8; nt++) {
#pragma unroll
        for (int kt = 0; kt < 4; kt++) {
            half8 af = *(const half8*)(Wt + ((size_t)nt * 4 + kt) * 512 + lane * 8);
            acc[nt] = __builtin_amdgcn_mfma_f32_16x16x32_f16(af, bf[kt], acc[nt], 0, 0, 0);
        }
    }
    float sv = skipv[l * TT + t];
    float beta = 1.f / (1.f + __expf(-sv));
    float xn[8][4];
    float s1 = 0.f, s2 = 0.f;
#pragma unroll
    for (int nt = 0; nt < 8; nt++) {
        int c0 = nt * 16 + quad * 4;
        float4 b4 = *(const float4*)(ba + (l * TT + t) * CC + c0);
        half2t x0 = __builtin_bit_cast(half2t, xw8[nt].x),
               x1 = __builtin_bit_cast(half2t, xw8[nt].y);
        float xv[4] = {(float)x0.x, (float)x0.y, (float)x1.x, (float)x1.y};
        float bb[4] = {b4.x, b4.y, b4.z, b4.w};
#pragma unroll
        for (int reg = 0; reg < 4; reg++) {
            float o = acc[nt][reg] + bb[reg];
            float v = beta * o + (1.f - beta) * xv[reg];
            xn[nt][reg] = v;
            s1 += v;
            s2 += v * v;
        }
    }
    s1 += __shfl_xor(s1, 16); s1 += __shfl_xor(s1, 32);
    s2 += __shfl_xor(s2, 16); s2 += __shfl_xor(s2, 32);
    float mu = s1 * (1.f / CC);
    float var = s2 * (1.f / CC) - mu * mu;
    float rs = rsqrtf(var + 1e-5f);
#pragma unroll
    for (int nt = 0; nt < 8; nt++) {
        int c0 = nt * 16 + quad * 4;
        float4 g4 = *(const float4*)(ln_g + (l * TT + t) * CC + c0);
        float4 be4 = *(const float4*)(ln_b + (l * TT + t) * CC + c0);
        float y0 = fmaxf((xn[nt][0] - mu) * rs * g4.x + be4.x, 0.f);
        float y1 = fmaxf((xn[nt][1] - mu) * rs * g4.y + be4.y, 0.f);
        float y2 = fmaxf((xn[nt][2] - mu) * rs * g4.z + be4.z, 0.f);
        float y3 = fmaxf((xn[nt][3] - mu) * rs * g4.w + be4.w, 0.f);
        if (xout) {
            // direct store: per wave, 16 rows x 64B contiguous per nt; all 8 nt
            // steps fully cover each 512B row -> full-line write combining in L2
            if (node < NN) {
                float4 o4 = {y0, y1, y2, y3};
                *(float4*)(xout + (size_t)node * CC + c0) = o4;
            }
        } else {
            uint2 o;
            o.x = pk2h(y0, y1);
            o.y = pk2h(y2, y3);
            *(uint2*)(smem_h + nloc * 132 + c0) = o;
        }
    }
    if (!xout) {
        __syncthreads();
        // swizzled coalesced copy-out: [tile][kt][lane][8], incl. pad tiles
        _Float16* xnt = xs_next + (size_t)t * NT16R * 2048;
#pragma unroll
        for (int p = 0; p < 4; p++) {
            int c = p * 256 + tid;
            int tl = c >> 8, kt2 = (c >> 6) & 3, l2 = c & 63;
            int q2 = l2 >> 4, ln2 = l2 & 15;
            *(uint4*)(xnt + ((size_t)(blockIdx.x * 4 + tl) * 4 + kt2) * 512 + l2 * 8) =
                *(const uint4*)(smem_h + (tl * 16 + ln2) * 132 + kt2 * 32 + q2 * 8);
        }
    }
}

extern "C" void kernel_launch(void* const* d_in, const int* in_sizes, int n_in,
                              void* d_out, int out_size, void* d_ws, size_t ws_size,
                              hipStream_t stream) {
    const float* x = (const float*)d_in[0];
    const int* ei = (const int*)d_in[1];
    const float* Wk = (const float*)d_in[2];
    const float* bk = (const float*)d_in[3];
    const float* Wq = (const float*)d_in[4];
    const float* bq = (const float*)d_in[5];
    const float* Wv = (const float*)d_in[6];
    const float* bv = (const float*)d_in[7];
    const float* Wa = (const float*)d_in[8];
    const float* ba = (const float*)d_in[9];
    const float* skip = (const float*)d_in[10];
    const float* a_rel = (const float*)d_in[11];
    const float* m_rel = (const float*)d_in[12];
    const float* p_rel = (const float*)d_in[13];
    const float* ln_g = (const float*)d_in[14];
    const float* ln_b = (const float*)d_in[15];

    char* ws = (char*)d_ws;
    size_t off = 0;
    auto alloc = [&](size_t b) {
        size_t o = off;
        off = (off + b + 255) & ~(size_t)255;
        return o;
    };
    _Float16* xsA = (_Float16*)(ws + alloc((size_t)TT * NT16R * 2048 * 2));
    _Float16* xsB = (_Float16*)(ws + alloc((size_t)TT * NT16R * 2048 * 2));
    unsigned char* qkv8 = (unsigned char*)(ws + alloc((size_t)TT * NN * 512));
    _Float16* outg = (_Float16*)(ws + alloc((size_t)TT * NN * CC * 2));
    _Float16* W2 = (_Float16*)(ws + alloc((size_t)2 * TT * 24 * 2048 * 2));
    _Float16* Wa2 = (_Float16*)(ws + alloc((size_t)2 * TT * 8 * 2048 * 2));
    float* beff = (float*)(ws + alloc((size_t)2 * TT * 384 * 4));
    int* counts = (int*)(ws + alloc((size_t)2 * NN * 4));
    unsigned short* rankb = (unsigned short*)(ws + alloc((size_t)2 * EE * 2));
    int* rowptr = (int*)(ws + alloc((size_t)2 * (NN + 1) * 4));
    int* csr = (int*)(ws + alloc((size_t)2 * EE * 4));
    int* bsum = (int*)(ws + alloc((size_t)2 * SCB * 4 + 256));
    (void)ws_size; (void)in_sizes; (void)n_in; (void)out_size;

    // fused: count | cvt | prep (all input-only dependencies; no memset needed
    // -- partitioned count writes every counts bin exactly once)
    k_fuse_pre<<<dim3(CNTB + CVTB + PREPB, 2), 256, 0, stream>>>(
        ei, counts, rankb, x, xsA, Wk, Wq, Wv, Wa, bk, bq, bv, a_rel, m_rel,
        p_rel, W2, Wa2, beff);
    k_scan1<<<dim3(SCB, 2), 256, 0, stream>>>(counts, rowptr, bsum);
    k_scan23<<<dim3(SCB, 2), 256, 0, stream>>>(rowptr, bsum);
    // fused: scatter | layer-0 gemm (independent after scan23 + fuse_pre)
    k_fuse_mid<<<dim3(EB + GB, 2), 256, 0, stream>>>(
        ei, rowptr, rankb, csr, xsA, W2, beff, qkv8);
    k_attn<<<dim3(NN / 4, 2), 256, 0, stream>>>(qkv8, rowptr, csr, outg);
    k_epilogue<<<dim3((NN + 63) / 64, 2), 256, 0, stream>>>(
        outg, Wa2, ba, skip, ln_g, ln_b, xsA, xsB, nullptr, 0);
    // layer 1: only t0 output needed -> t0 needs q cols [0,128), t1 needs k/v cols [128,384)
    k_gemm_l1<<<dim3(GB, 2), 256, 0, stream>>>(xsB, W2, beff, qkv8);
    k_attn<<<dim3(NN / 4, 1), 256, 0, stream>>>(qkv8, rowptr, csr, outg);
    k_epilogue<<<dim3((NN + 63) / 64, 1), 256, 0, stream>>>(
        outg, Wa2, ba, skip, ln_g, ln_b, xsB, nullptr, (float*)d_out, 1);
}

// Round 14
// 305.633 us; speedup vs baseline: 1.4128x; 1.4128x over previous
//
#include <hip/hip_runtime.h>

#define NN 50000
#define EE 400000
#define CC 128
#define TT 2
#define NT16R 3128  // padded 16-node tiles per type (ceil(50048/16))
#define KPB 8      // edges per thread in scatter batching
#define KPBC 16    // edges per thread in count batching (2x ILP on atomics)
#define SCB ((NN + 1023) / 1024)
#define EB ((EE + 256 * KPB - 1) / (256 * KPB))     // 196 scatter blocks per type
#define EBC ((EE + 256 * KPBC - 1) / (256 * KPBC))  // 98 count blocks per type
#define CVTB (NT16R / 4)                     // 782 cvt blocks per type
#define PREPN (2 * 384 * 128 + 2 * 128 * 128 + 2 * 384)
#define PREPB ((PREPN + 255) / 256)          // 515 prep blocks per layer
#define GB ((NN + 31) / 32)                  // 1563 gemm blocks per type

typedef float floatx4 __attribute__((ext_vector_type(4)));
typedef float floatx2 __attribute__((ext_vector_type(2)));
typedef _Float16 half8 __attribute__((ext_vector_type(8)));
typedef _Float16 half2t __attribute__((ext_vector_type(2)));

__device__ __forceinline__ unsigned pk2h(float a, float b) {
    return __builtin_bit_cast(unsigned, __builtin_amdgcn_cvt_pkrtz(a, b));
}
// tanh-approx gelu (jax.nn.gelu default approximate=True), NaN-free form
__device__ __forceinline__ float gelu_f(float x) {
    float u = 0.7978845608028654f * (x + 0.044715f * x * x * x);
    float t = __expf(2.f * u);
    return x * (1.f - 1.f / (t + 1.f));
}

// packed f32 fma: lowers to v_pk_fma_f32 on gfx90a+
__device__ __forceinline__ floatx2 pkfma(floatx2 a, floatx2 b, floatx2 c) {
#if __has_builtin(__builtin_elementwise_fma)
    return __builtin_elementwise_fma(a, b, c);
#else
    floatx2 r;
    r.x = fmaf(a.x, b.x, c.x);
    r.y = fmaf(a.y, b.y, c.y);
    return r;
#endif
}

// ---- OCP e4m3 pack/unpack (HW cvt on gfx950; SW fallback) ----
__device__ __forceinline__ unsigned pk_fp8x4(float a, float b, float c, float d) {
#if __has_builtin(__builtin_amdgcn_cvt_pk_fp8_f32)
    int v = 0;
    v = __builtin_amdgcn_cvt_pk_fp8_f32(a, b, v, false);
    v = __builtin_amdgcn_cvt_pk_fp8_f32(c, d, v, true);
    return (unsigned)v;
#else
    auto enc = [](float x) -> unsigned {
        unsigned u = __float_as_uint(x);
        unsigned s = (u >> 24) & 0x80;
        int e = (int)((u >> 23) & 0xff);
        unsigned m = u & 0x7fffff;
        if (e == 0) return s;
        int ne = e - 127 + 7;
        if (ne <= 0) {
            unsigned full = (1u << 23) | m;
            int sh = 21 - ne;
            if (sh > 24) return s;
            unsigned r = full >> sh;
            unsigned rem = full & ((1u << sh) - 1);
            unsigned half = 1u << (sh - 1);
            if (rem > half || (rem == half && (r & 1))) r++;
            return s | (r & 0x7f);
        }
        unsigned r = m >> 20;
        unsigned rem = m & 0xfffff;
        if (rem > 0x80000 || (rem == 0x80000 && (r & 1))) {
            r++;
            if (r == 8) { r = 0; ne++; }
        }
        if (ne > 15) return s | 0x7e;
        return s | ((unsigned)ne << 3) | r;
    };
    return enc(a) | (enc(b) << 8) | (enc(c) << 16) | (enc(d) << 24);
#endif
}

template <bool HI>
__device__ __forceinline__ floatx2 upk_fp8(unsigned v) {
#if __has_builtin(__builtin_amdgcn_cvt_pk_f32_fp8)
    return __builtin_amdgcn_cvt_pk_f32_fp8((int)v, HI);
#else
    auto dec = [](unsigned b) -> float {
        unsigned s = b & 0x80;
        unsigned e = (b >> 3) & 0xf;
        unsigned m = b & 7;
        float val;
        if (e == 0) val = (float)m * (1.f / 512.f);
        else val = (1.f + (float)m * 0.125f) * exp2f((float)e - 7.f);
        return s ? -val : val;
    };
    unsigned base = HI ? (v >> 16) : v;
    floatx2 r;
    r.x = dec(base & 0xff);
    r.y = dec((base >> 8) & 0xff);
    return r;
#endif
}

// block-local int64 probe: int64 node arrays have zero high words
__device__ __forceinline__ int detect_is64(const int* __restrict__ ei, int* sflag) {
    if (threadIdx.x == 0) {
        int orv = 0;
#pragma unroll
        for (int i = 1; i < 64; i += 2) orv |= ei[i];
        *sflag = (orv == 0) ? 1 : 0;
    }
    __syncthreads();
    return *sflag;
}

// Batched count: 16 edges/thread, atomics pipelined by ILP (16 in flight).
// Side product: per-edge within-node arrival rank (ushort) -> scatter needs no atomic.
__device__ __forceinline__ void count_body(const int* __restrict__ ei,
                                           int* __restrict__ counts,
                                           unsigned short* __restrict__ rank,
                                           int e, int bx, int* sflag) {
    int is64 = detect_is64(ei, sflag);
    int tid = threadIdx.x;
    int base = bx * (256 * KPBC);
    const size_t db = (size_t)(e * 2 + 1) * EE;
    int di[KPBC];
    bool val[KPBC];
#pragma unroll
    for (int k = 0; k < KPBC; k++) {
        int j = base + k * 256 + tid;
        val[k] = j < EE;
        int jc = val[k] ? j : 0;
        int d = is64 ? ei[(db + jc) * 2] : ei[db + jc];
        di[k] = min(max(d, 0), NN - 1);
    }
    int rk[KPBC];
#pragma unroll
    for (int k = 0; k < KPBC; k++)
        rk[k] = val[k] ? atomicAdd(&counts[e * NN + di[k]], 1) : 0;
#pragma unroll
    for (int k = 0; k < KPBC; k++) {
        int j = base + k * 256 + tid;
        if (val[k]) rank[(size_t)e * EE + j] = (unsigned short)rk[k];
    }
}

// Atomic-free scatter: pos = rowptr[di] + rank[j]; 8 edges/thread for ILP.
__device__ __forceinline__ void scatter_body(const int* __restrict__ ei,
                                             const int* __restrict__ rowptr,
                                             const unsigned short* __restrict__ rank,
                                             int* __restrict__ csr,
                                             int e, int bx, int* sflag) {
    int is64 = detect_is64(ei, sflag);
    int tid = threadIdx.x;
    int base = bx * (256 * KPB);
    const size_t sb = (size_t)(e * 2 + 0) * EE;
    const size_t db = (size_t)(e * 2 + 1) * EE;
    int si[KPB], di[KPB], rk[KPB];
#pragma unroll
    for (int k = 0; k < KPB; k++) {
        int j = base + k * 256 + tid;
        int jc = (j < EE) ? j : 0;
        si[k] = is64 ? ei[(sb + jc) * 2] : ei[sb + jc];
        di[k] = is64 ? ei[(db + jc) * 2] : ei[db + jc];
        rk[k] = rank[(size_t)e * EE + jc];
    }
    int pos[KPB];
#pragma unroll
    for (int k = 0; k < KPB; k++) {
        di[k] = min(max(di[k], 0), NN - 1);
        si[k] = min(max(si[k], 0), NN - 1);
    }
#pragma unroll
    for (int k = 0; k < KPB; k++) pos[k] = rowptr[e * (NN + 1) + di[k]] + rk[k];
#pragma unroll
    for (int k = 0; k < KPB; k++) {
        int j = base + k * 256 + tid;
        if (j < EE) csr[(size_t)e * EE + pos[k]] = si[k];
    }
}

// cvt: x f32 row-major -> xs f16 swizzled [t][tile][kt][quad][ln][8] via LDS
// transpose.  Pad tiles filled with clamped rows.  Both global sides coalesced.
__device__ __forceinline__ void cvt_body(const float* __restrict__ x,
                                         _Float16* __restrict__ xs,
                                         int t, int bx, _Float16* sm) {
    int tid = threadIdx.x;
    int node0 = bx * 64;
#pragma unroll
    for (int p = 0; p < 8; p++) {
        int c = p * 256 + tid;
        int row = c >> 5, ch = c & 31;
        int node = min(node0 + row, NN - 1);
        float4 v = *(const float4*)(x + ((size_t)t * NN + node) * CC + ch * 4);
        uint2 o;
        o.x = pk2h(v.x, v.y);
        o.y = pk2h(v.z, v.w);
        *(uint2*)(sm + row * 132 + ch * 4) = o;
    }
    __syncthreads();
    _Float16* xt = xs + (size_t)t * NT16R * 2048;
#pragma unroll
    for (int p = 0; p < 4; p++) {
        int c = p * 256 + tid;
        int tl = c >> 8, kt = (c >> 6) & 3, l = c & 63;
        int q = l >> 4, ln = l & 15;
        *(uint4*)(xt + ((size_t)(bx * 4 + tl) * 4 + kt) * 512 + l * 8) =
            *(const uint4*)(sm + (tl * 16 + ln) * 132 + kt * 32 + q * 8);
    }
}

// prep: composed weights (idx-based mapping), swizzled A-frag layout:
//   W2[lt][mt(24)][kt(4)][lane(64)][8]; n in [0,384):
//   q*p_rel*scale*log2e | Wk a_rel | Wv m_rel  (log2e folded -> attn uses exp2)
__device__ __forceinline__ void prep_body(
    const float* __restrict__ Wk, const float* __restrict__ Wq,
    const float* __restrict__ Wv, const float* __restrict__ Wa,
    const float* __restrict__ bk, const float* __restrict__ bq,
    const float* __restrict__ bv,
    const float* __restrict__ a_rel, const float* __restrict__ m_rel,
    const float* __restrict__ p_rel,
    _Float16* __restrict__ W2, _Float16* __restrict__ Wa2,
    float* __restrict__ beff, int l, int idx) {
    // 1/sqrt(32) * log2(e): softmax(exp2(x*log2e)) == softmax(exp(x))
    const float SCALE = 0.17677669529663687f * 1.4426950408889634f;
    if (idx < 2 * 384 * 128) {
        int t = idx / (384 * 128);
        int r = idx - t * 384 * 128;
        int n = r >> 7, k = r & 127;
        float val;
        if (n < 128) {
            val = Wq[((l * 2 + t) * 128 + k) * 128 + n] *
                  p_rel[(l * 2 + (1 - t)) * 4 + (n >> 5)] * SCALE;
        } else if (n < 256) {
            int nn = n - 128, h = nn >> 5, f = nn & 31;
            const float* wr = Wk + ((l * 2 + t) * 128 + k) * 128 + h * 32;
            const float* ar = a_rel + (((l * 2 + t) * 4 + h) * 32) * 32 + f;
            float s = 0.f;
            for (int d = 0; d < 32; d++) s += wr[d] * ar[d * 32];
            val = s;
        } else {
            int nn = n - 256, h = nn >> 5, f = nn & 31;
            const float* wr = Wv + ((l * 2 + t) * 128 + k) * 128 + h * 32;
            const float* mr = m_rel + (((l * 2 + t) * 4 + h) * 32) * 32 + f;
            float s = 0.f;
            for (int d = 0; d < 32; d++) s += wr[d] * mr[d * 32];
            val = s;
        }
        W2[(((size_t)(l * 2 + t) * 24 + (n >> 4)) * 4 + (k >> 5)) * 512 +
           (((k & 31) >> 3) * 16 + (n & 15)) * 8 + (k & 7)] = (_Float16)val;
    } else if (idx < 2 * 384 * 128 + 2 * 128 * 128) {
        int r = idx - 2 * 384 * 128;
        int t = r / (128 * 128);
        r -= t * 128 * 128;
        int n = r >> 7, k = r & 127;
        float val = Wa[((l * 2 + t) * 128 + k) * 128 + n];
        Wa2[(((size_t)(l * 2 + t) * 8 + (n >> 4)) * 4 + (k >> 5)) * 512 +
            (((k & 31) >> 3) * 16 + (n & 15)) * 8 + (k & 7)] = (_Float16)val;
    } else if (idx < PREPN) {
        int r = idx - (2 * 384 * 128 + 2 * 128 * 128);
        int t = r / 384, n = r - t * 384;
        float val;
        if (n < 128) {
            val = bq[(l * 2 + t) * 128 + n] * p_rel[(l * 2 + (1 - t)) * 4 + (n >> 5)] * SCALE;
        } else if (n < 256) {
            int nn = n - 128, h = nn >> 5, f = nn & 31;
            float s = 0.f;
            for (int d = 0; d < 32; d++)
                s += bk[(l * 2 + t) * 128 + h * 32 + d] *
                     a_rel[(((l * 2 + t) * 4 + h) * 32 + d) * 32 + f];
            val = s;
        } else {
            int nn = n - 256, h = nn >> 5, f = nn & 31;
            float s = 0.f;
            for (int d = 0; d < 32; d++)
                s += bv[(l * 2 + t) * 128 + h * 32 + d] *
                     m_rel[(((l * 2 + t) * 4 + h) * 32 + d) * 32 + f];
            val = s;
        }
        beff[(l * 2 + t) * 384 + n] = val;
    }
}

// FUSED independent pre-work: count (x<EBC) | cvt (x<EBC+CVTB) | prep (rest).
// All three depend only on kernel inputs; co-scheduling hides the count
// atomics' latency under cvt/prep memory work.
__global__ __launch_bounds__(256) void k_fuse_pre(
    const int* __restrict__ ei, int* __restrict__ counts,
    unsigned short* __restrict__ rank,
    const float* __restrict__ x, _Float16* __restrict__ xs,
    const float* __restrict__ Wk, const float* __restrict__ Wq,
    const float* __restrict__ Wv, const float* __restrict__ Wa,
    const float* __restrict__ bk, const float* __restrict__ bq,
    const float* __restrict__ bv,
    const float* __restrict__ a_rel, const float* __restrict__ m_rel,
    const float* __restrict__ p_rel,
    _Float16* __restrict__ W2, _Float16* __restrict__ Wa2,
    float* __restrict__ beff) {
    __shared__ _Float16 sm[64 * 132];
    __shared__ int sflag;
    if (blockIdx.x < EBC) {
        count_body(ei, counts, rank, blockIdx.y, blockIdx.x, &sflag);
    } else if (blockIdx.x < EBC + CVTB) {
        cvt_body(x, xs, blockIdx.y, blockIdx.x - EBC, sm);
    } else {
        prep_body(Wk, Wq, Wv, Wa, bk, bq, bv, a_rel, m_rel, p_rel, W2, Wa2, beff,
                  blockIdx.y, (blockIdx.x - EBC - CVTB) * 256 + (int)threadIdx.x);
    }
}

// ---- scan phase 1: per-block local prefixes + raw block sums ----
__global__ __launch_bounds__(256) void k_scan1(const int* __restrict__ counts,
                                               int* __restrict__ rowptr,
                                               int* __restrict__ bsum) {
    int e = blockIdx.y, b = blockIdx.x;
    int tid = threadIdx.x, lane = tid & 63, wid = tid >> 6;
    __shared__ int wsum[4];
    int base = b * 1024 + tid * 4;
    int v[4], s = 0;
#pragma unroll
    for (int k2 = 0; k2 < 4; k2++) {
        int i = base + k2;
        v[k2] = (i < NN) ? counts[e * NN + i] : 0;
        s += v[k2];
    }
    int incl = s;
#pragma unroll
    for (int off = 1; off < 64; off <<= 1) {
        int t2 = __shfl_up(incl, off);
        if (lane >= off) incl += t2;
    }
    if (lane == 63) wsum[wid] = incl;
    __syncthreads();
    int woff = 0;
    for (int w2 = 0; w2 < wid; w2++) woff += wsum[w2];
    int excl = woff + incl - s;
#pragma unroll
    for (int k2 = 0; k2 < 4; k2++) {
        int i = base + k2;
        if (i < NN) rowptr[e * (NN + 1) + i] = excl;
        excl += v[k2];
    }
    if (tid == 255) bsum[e * SCB + b] = woff + incl;
}

// ---- scan phase 2+3 merged: each block re-scans the 49 raw block sums
// itself (one wave), derives its own offset + grand total, applies. ----
__global__ __launch_bounds__(256) void k_scan23(int* __restrict__ rowptr,
                                                const int* __restrict__ bsum) {
    __shared__ int soff2[2];  // {block offset, grand total}
    int e = blockIdx.y, b = blockIdx.x;
    int tid = threadIdx.x, lane = tid & 63, wv = tid >> 6;
    if (wv == 0) {
        int v = (lane < SCB) ? bsum[e * SCB + lane] : 0;
        int incl = v;
#pragma unroll
        for (int off = 1; off < 64; off <<= 1) {
            int t2 = __shfl_up(incl, off);
            if (lane >= off) incl += t2;
        }
        if (lane == b) soff2[0] = incl - v;         // exclusive prefix at b
        if (lane == SCB - 1) soff2[1] = incl;       // total
    }
    __syncthreads();
    int off = soff2[0];
    int base = b * 1024 + tid * 4;
#pragma unroll
    for (int k2 = 0; k2 < 4; k2++) {
        int i = base + k2;
        if (i < NN) rowptr[e * (NN + 1) + i] += off;
    }
    if (b == 0 && tid == 0) rowptr[e * (NN + 1) + NN] = soff2[1];
}

// Transposed GEMM body, swizzled operands (every frag load = base + lane*16,
// coalesced), LDS-staged coalesced stores into mixed-precision qkv rows:
// node row = 512 B: [0,256) q f16 | [256,512) k/v fp8 INTERLEAVED in 16B granules:
//   granule g (byte 256+g*16): k feats [g*8,g*8+8) | v feats [g*8,g*8+8).
template <int NT, int COL0>
__device__ __forceinline__ void gemm_body(const _Float16* __restrict__ xs,
                                          const _Float16* __restrict__ W2,
                                          const float* __restrict__ beff,
                                          unsigned char* __restrict__ qkv8,
                                          int l, int t, int bx,
                                          unsigned char* tile) {
    constexpr int RB = (NT == 6) ? 512 : 256;  // tile row bytes
    constexpr int RS = RB + 16;                // LDS row stride
    int tid = threadIdx.x;
    int wid = tid >> 6, lane = tid & 63;
    int quad = lane >> 4, ln = lane & 15;
    int node0 = bx * 32;
    int tile0 = bx * 2;
    int lt = l * 2 + t;
    const _Float16* Wt = W2 + (size_t)lt * 24 * 2048;
    const _Float16* xt = xs + (size_t)t * NT16R * 2048;
    half8 bf[2][4];
#pragma unroll
    for (int ns = 0; ns < 2; ns++)
#pragma unroll
        for (int kt = 0; kt < 4; kt++)
            bf[ns][kt] = *(const half8*)(xt + ((size_t)(tile0 + ns) * 4 + kt) * 512 + lane * 8);
    floatx4 acc[NT][2];
#pragma unroll
    for (int nt = 0; nt < NT; nt++)
#pragma unroll
        for (int ns = 0; ns < 2; ns++) acc[nt][ns] = (floatx4){0.f, 0.f, 0.f, 0.f};
#pragma unroll
    for (int nt = 0; nt < NT; nt++) {
        int mt = COL0 / 16 + wid * NT + nt;
#pragma unroll
        for (int kt = 0; kt < 4; kt++) {
            half8 af = *(const half8*)(Wt + ((size_t)mt * 4 + kt) * 512 + lane * 8);
            acc[nt][0] = __builtin_amdgcn_mfma_f32_16x16x32_f16(af, bf[0][kt], acc[nt][0], 0, 0, 0);
            acc[nt][1] = __builtin_amdgcn_mfma_f32_16x16x32_f16(af, bf[1][kt], acc[nt][1], 0, 0, 0);
        }
    }
    // stage to LDS (+bias): q comps -> f16 pairs, k/v comps -> fp8x4 interleaved granules
#pragma unroll
    for (int nt = 0; nt < NT; nt++) {
        int c0 = COL0 + wid * NT * 16 + nt * 16 + quad * 4;
        float4 b4 = *(const float4*)(beff + (l * 2 + t) * 384 + c0);
#pragma unroll
        for (int ns = 0; ns < 2; ns++) {
            int nl = ns * 16 + ln;
            float v0 = acc[nt][ns][0] + b4.x, v1 = acc[nt][ns][1] + b4.y;
            float v2 = acc[nt][ns][2] + b4.z, v3 = acc[nt][ns][3] + b4.w;
            unsigned char* rowp = tile + nl * RS;
            if (c0 < 128) {
                uint2 o;
                o.x = pk2h(v0, v1);
                o.y = pk2h(v2, v3);
                *(uint2*)(rowp + 2 * c0) = o;
            } else {
                int f0 = c0 & 127;            // feature index within k (or v)
                int isV = (c0 >= 256);
                int loff = (f0 >> 3) * 16 + (f0 & 7) + isV * 8 +
                           ((COL0 == 128) ? 0 : 256);
                *(unsigned*)(rowp + loff) = pk_fp8x4(v0, v1, v2, v3);
            }
        }
    }
    __syncthreads();
    // coalesced copy-out: 16B chunks, contiguous RB bytes per node row
    constexpr int CPR = RB / 16;
    constexpr int PASSES = (32 * CPR) / 256;
#pragma unroll
    for (int p = 0; p < PASSES; p++) {
        int c = p * 256 + tid;
        int row = c / CPR, ch = c - row * CPR;
        int node = node0 + row;
        if (node < NN)
            *(uint4*)(qkv8 + ((size_t)t * NN + node) * 512 + (COL0 ? 256 : 0) + ch * 16) =
                *(const uint4*)(tile + row * RS + ch * 16);
    }
}

// FUSED mid stage: scatter (x<EB) | layer-0 full-qkv GEMM (rest).
// scatter needs {rowptr, rank} (ready after scan23); gemm needs {xs, W2, beff}
// (ready after fuse_pre) -> independent, co-scheduled.  Scatter's scattered
// stores hide under the GEMM's MFMA work.
__global__ __launch_bounds__(256) void k_fuse_mid(
    const int* __restrict__ ei, const int* __restrict__ rowptr,
    const unsigned short* __restrict__ rank, int* __restrict__ csr,
    const _Float16* __restrict__ xs, const _Float16* __restrict__ W2,
    const float* __restrict__ beff, unsigned char* __restrict__ qkv8) {
    __shared__ unsigned char tile[32 * 528];  // gemm<6,0>: RS=528
    if (blockIdx.x < EB) {
        scatter_body(ei, rowptr, rank, csr, blockIdx.y, blockIdx.x, (int*)tile);
    } else {
        gemm_body<6, 0>(xs, W2, beff, qkv8, 0, blockIdx.y, blockIdx.x - EB, tile);
    }
}

// Layer-1 merged pair: y=0 -> t0 q cols [0,128); y=1 -> t1 k/v cols [128,384).
__global__ __launch_bounds__(256) void k_gemm_l1(const _Float16* __restrict__ xs,
                                                 const _Float16* __restrict__ W2,
                                                 const float* __restrict__ beff,
                                                 unsigned char* __restrict__ qkv8) {
    __shared__ unsigned char tile[32 * 272];  // RB=256 for both branches
    if (blockIdx.y == 0)
        gemm_body<2, 0>(xs, W2, beff, qkv8, 1, 0, blockIdx.x, tile);
    else
        gemm_body<4, 128>(xs, W2, beff, qkv8, 1, 1, blockIdx.x, tile);
}

// Dest-centric attention.  Wave = 1 dest node; 64 lanes = 4 edge slots x 16 segs.
// q f16; k/v fp8 interleaved 16B granules -> ONE uint4 gather per lane per edge.
// csr indices prefetched one chunk ahead of gathers (breaks the csr->gather
// serial latency chain); rowptr via scalar loads; tail slots exec-masked.
// Logits arrive pre-scaled by log2e (prep) -> exp2 for softmax.
__global__ __launch_bounds__(256) void k_attn(const unsigned char* __restrict__ qkv8,
                                              const int* __restrict__ rowptr,
                                              const int* __restrict__ csr,
                                              _Float16* __restrict__ outg) {
    int t = blockIdx.y;
    int e = 1 - t;
    int st = 1 - t;
    int wid = threadIdx.x >> 6, lane = threadIdx.x & 63;
    int n = __builtin_amdgcn_readfirstlane(blockIdx.x * 4 + wid);
    int e4 = lane >> 4, s = lane & 15;
    // n is SGPR -> these become scalar loads issued on the scalar pipe
    int r0 = rowptr[e * (NN + 1) + n];
    int r1 = rowptr[e * (NN + 1) + n + 1];
    const int* csrp = csr + (size_t)e * EE;
    const unsigned char* sbase = qkv8 + (size_t)st * NN * 512;
    uint4 qd = *(const uint4*)(qkv8 + ((size_t)t * NN + n) * 512 + s * 16);

    floatx2 acc2[4];
#pragma unroll
    for (int i = 0; i < 4; i++) acc2[i] = (floatx2){0.f, 0.f};
    float lsum = 0.f;
    floatx2 q2[4];

    auto process = [&](const uint4& u, float msk) {
        // u.x|u.y = k feats [s*8, s*8+8); u.z|u.w = v feats [s*8, s*8+8)
        floatx2 p2 = q2[0] * upk_fp8<false>(u.x);
        p2 = pkfma(q2[1], upk_fp8<true>(u.x), p2);
        p2 = pkfma(q2[2], upk_fp8<false>(u.y), p2);
        p2 = pkfma(q2[3], upk_fp8<true>(u.y), p2);
        float p = p2.x + p2.y;
        p += __shfl_xor(p, 1);
        p += __shfl_xor(p, 2);  // 4 segs of one head now hold the full head dot
        float w = exp2f(p) * msk;  // q pre-scaled by log2e
        lsum += w;
        floatx2 w2 = (floatx2){w, w};
        acc2[0] = pkfma(w2, upk_fp8<false>(u.z), acc2[0]);
        acc2[1] = pkfma(w2, upk_fp8<true>(u.z), acc2[1]);
        acc2[2] = pkfma(w2, upk_fp8<false>(u.w), acc2[2]);
        acc2[3] = pkfma(w2, upk_fp8<true>(u.w), acc2[3]);
    };

    if (r0 < r1) {
        int j = r0;
        // prologue: csr indices for chunks j and j+4 both in flight, then gather j
        int iA = csrp[min(j + e4, r1 - 1)];
        int iB = csrp[min(j + 4 + e4, r1 - 1)];
        uint4 uA = (uint4){0u, 0u, 0u, 0u};
        if (j + e4 < r1) uA = *(const uint4*)(sbase + (size_t)iA * 512 + 256 + s * 16);
        // convert q while the loads fly
        {
            half2t h0 = __builtin_bit_cast(half2t, qd.x), h1 = __builtin_bit_cast(half2t, qd.y);
            half2t h2 = __builtin_bit_cast(half2t, qd.z), h3 = __builtin_bit_cast(half2t, qd.w);
            q2[0] = (floatx2){(float)h0.x, (float)h0.y};
            q2[1] = (floatx2){(float)h1.x, (float)h1.y};
            q2[2] = (floatx2){(float)h2.x, (float)h2.y};
            q2[3] = (floatx2){(float)h3.x, (float)h3.y};
        }
        for (; j + 8 < r1; j += 4) {
            // chunk j+4 is fully valid here (j+4+e4 <= j+7 < r1)
            uint4 uB = *(const uint4*)(sbase + (size_t)iB * 512 + 256 + s * 16);
            iB = csrp[min(j + 8 + e4, r1 - 1)];  // prefetch indices one chunk ahead
            process(uA, 1.f);
            uA = uB;
        }
        if (j + 4 < r1) {
            // chunk j full, chunk j+4 partial
            uint4 uB = (uint4){0u, 0u, 0u, 0u};
            float mB = (j + 4 + e4 < r1) ? 1.f : 0.f;
            if (j + 4 + e4 < r1)
                uB = *(const uint4*)(sbase + (size_t)iB * 512 + 256 + s * 16);
            process(uA, 1.f);
            process(uB, mB);
        } else {
            process(uA, (j + e4 < r1) ? 1.f : 0.f);
        }
    }
    float accf[8] = {acc2[0].x, acc2[0].y, acc2[1].x, acc2[1].y,
                     acc2[2].x, acc2[2].y, acc2[3].x, acc2[3].y};
#pragma unroll
    for (int i = 0; i < 8; i++) {
        accf[i] += __shfl_xor(accf[i], 16);
        accf[i] += __shfl_xor(accf[i], 32);
    }
    lsum += __shfl_xor(lsum, 16);
    lsum += __shfl_xor(lsum, 32);
    float inv = 1.f / (lsum + 1e-16f);
    if (e4 == 0) {
        uint4 o;
        o.x = pk2h(accf[0] * inv, accf[1] * inv);
        o.y = pk2h(accf[2] * inv, accf[3] * inv);
        o.z = pk2h(accf[4] * inv, accf[5] * inv);
        o.w = pk2h(accf[6] * inv, accf[7] * inv);
        *(uint4*)(outg + ((size_t)t * NN + n) * CC + s * 8) = o;
    }
}

// Transposed epilogue, swizzled Wa/x operands.
// o = gelu(outg) @ Wa + ba ; skip-blend ; LayerNorm ; ReLU.
// f16 path: LDS-staged swizzled xb_next writes (16.9 KB LDS -> 8 blocks/CU).
// f32 path (l=1): DIRECT float4 stores (no LDS, no barriers).
// Residual xs loads issued before the MFMA loop to hide their latency.
__global__ __launch_bounds__(256) void k_epilogue(
    const _Float16* __restrict__ outg, const _Float16* __restrict__ Wa2,
    const float* __restrict__ ba, const float* __restrict__ skipv,
    const float* __restrict__ ln_g, const float* __restrict__ ln_b,
    const _Float16* __restrict__ xs_cur, _Float16* __restrict__ xs_next,
    float* __restrict__ xout, int l) {
    __shared__ _Float16 smem_h[64 * 132];  // f16-only staging (f32 path bypasses LDS)
    int t = blockIdx.y;
    int tid = threadIdx.x;
    int wid = tid >> 6, lane = tid & 63;
    int quad = lane >> 4, ln = lane & 15;
    int node0 = blockIdx.x * 64;
    int nloc = wid * 16 + ln;
    int node = node0 + nloc;
    int arow = min(node, NN - 1);
    const _Float16* grow = outg + ((size_t)t * NN + arow) * CC;
    // issue all gelu-input loads first
    uint4 gd4[4];
#pragma unroll
    for (int kt = 0; kt < 4; kt++) gd4[kt] = *(const uint4*)(grow + kt * 32 + quad * 8);
    // issue residual loads early: their latency hides under gelu + MFMA
    const _Float16* xt = xs_cur + (size_t)t * NT16R * 2048;
    int tileR = arow >> 4, lnR = arow & 15;
    uint2 xw8[8];
#pragma unroll
    for (int nt = 0; nt < 8; nt++) {
        int c0 = nt * 16 + quad * 4;
        xw8[nt] = *(const uint2*)(xt + ((size_t)tileR * 4 + (c0 >> 5)) * 512 +
                                  (((c0 >> 3) & 3) * 16 + lnR) * 8 + (c0 & 7));
    }
    half8 bf[4];
#pragma unroll
    for (int kt = 0; kt < 4; kt++) {
        uint4 gd = gd4[kt];
        half2t h0 = __builtin_bit_cast(half2t, gd.x), h1 = __builtin_bit_cast(half2t, gd.y);
        half2t h2 = __builtin_bit_cast(half2t, gd.z), h3 = __builtin_bit_cast(half2t, gd.w);
        uint4 pk;
        pk.x = pk2h(gelu_f((float)h0.x), gelu_f((float)h0.y));
        pk.y = pk2h(gelu_f((float)h1.x), gelu_f((float)h1.y));
        pk.z = pk2h(gelu_f((float)h2.x), gelu_f((float)h2.y));
        pk.w = pk2h(gelu_f((float)h3.x), gelu_f((float)h3.y));
        bf[kt] = __builtin_bit_cast(half8, pk);
    }
    const _Float16* Wt = Wa2 + (size_t)(l * 2 + t) * 8 * 2048;
    floatx4 acc[8];
#pragma unroll
    for (int nt = 0; nt < 8; nt++) acc[nt] = (floatx4){0.f, 0.f, 0.f, 0.f};
#pragma unroll
    for (int nt = 0; nt < 8; nt++) {
#pragma unroll
        for (int kt = 0; kt < 4; kt++) {
            half8 af = *(const half8*)(Wt + ((size_t)nt * 4 + kt) * 512 + lane * 8);
            acc[nt] = __builtin_amdgcn_mfma_f32_16x16x32_f16(af, bf[kt], acc[nt], 0, 0, 0);
        }
    }
    float sv = skipv[l * TT + t];
    float beta = 1.f / (1.f + __expf(-sv));
    float xn[8][4];
    float s1 = 0.f, s2 = 0.f;
#pragma unroll
    for (int nt = 0; nt < 8; nt++) {
        int c0 = nt * 16 + quad * 4;
        float4 b4 = *(const float4*)(ba + (l * TT + t) * CC + c0);
        half2t x0 = __builtin_bit_cast(half2t, xw8[nt].x),
               x1 = __builtin_bit_cast(half2t, xw8[nt].y);
        float xv[4] = {(float)x0.x, (float)x0.y, (float)x1.x, (float)x1.y};
        float bb[4] = {b4.x, b4.y, b4.z, b4.w};
#pragma unroll
        for (int reg = 0; reg < 4; reg++) {
            float o = acc[nt][reg] + bb[reg];
            float v = beta * o + (1.f - beta) * xv[reg];
            xn[nt][reg] = v;
            s1 += v;
            s2 += v * v;
        }
    }
    s1 += __shfl_xor(s1, 16); s1 += __shfl_xor(s1, 32);
    s2 += __shfl_xor(s2, 16); s2 += __shfl_xor(s2, 32);
    float mu = s1 * (1.f / CC);
    float var = s2 * (1.f / CC) - mu * mu;
    float rs = rsqrtf(var + 1e-5f);
#pragma unroll
    for (int nt = 0; nt < 8; nt++) {
        int c0 = nt * 16 + quad * 4;
        float4 g4 = *(const float4*)(ln_g + (l * TT + t) * CC + c0);
        float4 be4 = *(const float4*)(ln_b + (l * TT + t) * CC + c0);
        float y0 = fmaxf((xn[nt][0] - mu) * rs * g4.x + be4.x, 0.f);
        float y1 = fmaxf((xn[nt][1] - mu) * rs * g4.y + be4.y, 0.f);
        float y2 = fmaxf((xn[nt][2] - mu) * rs * g4.z + be4.z, 0.f);
        float y3 = fmaxf((xn[nt][3] - mu) * rs * g4.w + be4.w, 0.f);
        if (xout) {
            // direct store: per wave, 16 rows x 64B contiguous per nt; all 8 nt
            // steps fully cover each 512B row -> full-line write combining in L2
            if (node < NN) {
                float4 o4 = {y0, y1, y2, y3};
                *(float4*)(xout + (size_t)node * CC + c0) = o4;
            }
        } else {
            uint2 o;
            o.x = pk2h(y0, y1);
            o.y = pk2h(y2, y3);
            *(uint2*)(smem_h + nloc * 132 + c0) = o;
        }
    }
    if (!xout) {
        __syncthreads();
        // swizzled coalesced copy-out: [tile][kt][lane][8], incl. pad tiles
        _Float16* xnt = xs_next + (size_t)t * NT16R * 2048;
#pragma unroll
        for (int p = 0; p < 4; p++) {
            int c = p * 256 + tid;
            int tl = c >> 8, kt2 = (c >> 6) & 3, l2 = c & 63;
            int q2 = l2 >> 4, ln2 = l2 & 15;
            *(uint4*)(xnt + ((size_t)(blockIdx.x * 4 + tl) * 4 + kt2) * 512 + l2 * 8) =
                *(const uint4*)(smem_h + (tl * 16 + ln2) * 132 + kt2 * 32 + q2 * 8);
        }
    }
}

extern "C" void kernel_launch(void* const* d_in, const int* in_sizes, int n_in,
                              void* d_out, int out_size, void* d_ws, size_t ws_size,
                              hipStream_t stream) {
    const float* x = (const float*)d_in[0];
    const int* ei = (const int*)d_in[1];
    const float* Wk = (const float*)d_in[2];
    const float* bk = (const float*)d_in[3];
    const float* Wq = (const float*)d_in[4];
    const float* bq = (const float*)d_in[5];
    const float* Wv = (const float*)d_in[6];
    const float* bv = (const float*)d_in[7];
    const float* Wa = (const float*)d_in[8];
    const float* ba = (const float*)d_in[9];
    const float* skip = (const float*)d_in[10];
    const float* a_rel = (const float*)d_in[11];
    const float* m_rel = (const float*)d_in[12];
    const float* p_rel = (const float*)d_in[13];
    const float* ln_g = (const float*)d_in[14];
    const float* ln_b = (const float*)d_in[15];

    char* ws = (char*)d_ws;
    size_t off = 0;
    auto alloc = [&](size_t b) {
        size_t o = off;
        off = (off + b + 255) & ~(size_t)255;
        return o;
    };
    _Float16* xsA = (_Float16*)(ws + alloc((size_t)TT * NT16R * 2048 * 2));
    _Float16* xsB = (_Float16*)(ws + alloc((size_t)TT * NT16R * 2048 * 2));
    unsigned char* qkv8 = (unsigned char*)(ws + alloc((size_t)TT * NN * 512));
    _Float16* outg = (_Float16*)(ws + alloc((size_t)TT * NN * CC * 2));
    _Float16* W2 = (_Float16*)(ws + alloc((size_t)2 * TT * 24 * 2048 * 2));
    _Float16* Wa2 = (_Float16*)(ws + alloc((size_t)2 * TT * 8 * 2048 * 2));
    float* beff = (float*)(ws + alloc((size_t)2 * TT * 384 * 4));
    int* counts = (int*)(ws + alloc((size_t)2 * NN * 4));
    unsigned short* rankb = (unsigned short*)(ws + alloc((size_t)2 * EE * 2));
    int* rowptr = (int*)(ws + alloc((size_t)2 * (NN + 1) * 4));
    int* csr = (int*)(ws + alloc((size_t)2 * EE * 4));
    int* bsum = (int*)(ws + alloc((size_t)2 * SCB * 4 + 256));
    (void)ws_size; (void)in_sizes; (void)n_in; (void)out_size;

    (void)hipMemsetAsync(counts, 0, (size_t)2 * NN * 4, stream);
    // fused: count | cvt | prep (all input-only dependencies)
    k_fuse_pre<<<dim3(EBC + CVTB + PREPB, 2), 256, 0, stream>>>(
        ei, counts, rankb, x, xsA, Wk, Wq, Wv, Wa, bk, bq, bv, a_rel, m_rel,
        p_rel, W2, Wa2, beff);
    k_scan1<<<dim3(SCB, 2), 256, 0, stream>>>(counts, rowptr, bsum);
    k_scan23<<<dim3(SCB, 2), 256, 0, stream>>>(rowptr, bsum);
    // fused: scatter | layer-0 gemm (independent after scan23 + fuse_pre)
    k_fuse_mid<<<dim3(EB + GB, 2), 256, 0, stream>>>(
        ei, rowptr, rankb, csr, xsA, W2, beff, qkv8);
    k_attn<<<dim3(NN / 4, 2), 256, 0, stream>>>(qkv8, rowptr, csr, outg);
    k_epilogue<<<dim3((NN + 63) / 64, 2), 256, 0, stream>>>(
        outg, Wa2, ba, skip, ln_g, ln_b, xsA, xsB, nullptr, 0);
    // layer 1: only t0 output needed -> t0 needs q cols [0,128), t1 needs k/v cols [128,384)
    k_gemm_l1<<<dim3(GB, 2), 256, 0, stream>>>(xsB, W2, beff, qkv8);
    k_attn<<<dim3(NN / 4, 1), 256, 0, stream>>>(qkv8, rowptr, csr, outg);
    k_epilogue<<<dim3((NN + 63) / 64, 1), 256, 0, stream>>>(
        outg, Wa2, ba, skip, ln_g, ln_b, xsB, nullptr, (float*)d_out, 1);
}